// Round 13
// baseline (440.056 us; speedup 1.0000x reference)
//
#include <hip/hip_runtime.h>
#include <hip/hip_fp16.h>

#define N_NODES  100000
#define NPAD     100032     // 1563*64, gemm grid padding (s1 padded to this)
#define N_EDGES  1600000
#define N_GRAPHS 64

#define BINSH  8
#define NBIN   392          // ceil(100000 / 256)
#define BINCAP 6144         // Poisson(4096) max ~4.5K; 1.5x headroom
#define EPB    2048         // edges per block in k_binA

typedef _Float16 half8 __attribute__((ext_vector_type(8)));
typedef float float4v __attribute__((ext_vector_type(4)));

__device__ __forceinline__ float lrelu(float v) { return v > 0.f ? v : 0.2f * v; }
__device__ __forceinline__ float elu_f(float v) { return v > 0.f ? v : __expf(v) - 1.f; }

// ---- Pass A: coarse-bin edges (dst>>8) into per-bin regions, coalesced runs.
__global__ __launch_bounds__(512) void k_binA(
    const int* __restrict__ src, const int* __restrict__ dst,
    const int* __restrict__ batch, int* __restrict__ gbin_cursor,
    int* __restrict__ cnt, int2* __restrict__ binned) {
    __shared__ int hist[NBIN], lexcl[NBIN], runbase[NBIN], lcur[NBIN];
    __shared__ int wpart[8];
    __shared__ int gh[N_GRAPHS];
    __shared__ int2 stage[EPB];
    int t = threadIdx.x;
    int e0 = blockIdx.x * EPB;
    for (int b = t; b < NBIN; b += 512) hist[b] = 0;
    if (t < N_GRAPHS) gh[t] = 0;
    __syncthreads();
    int nid = blockIdx.x * 512 + t;   // 782*512 >= N_NODES
    if (nid < N_NODES) atomicAdd(&gh[batch[nid]], 1);
    int e = 4 * t;                    // block-local edge base
    int4 dv = make_int4(0, 0, 0, 0), sv = make_int4(0, 0, 0, 0);
    bool full = (e0 + e + 3 < N_EDGES);
    if (full) {
        dv = *(const int4*)(dst + e0 + e);
        sv = *(const int4*)(src + e0 + e);
        atomicAdd(&hist[dv.x >> BINSH], 1);
        atomicAdd(&hist[dv.y >> BINSH], 1);
        atomicAdd(&hist[dv.z >> BINSH], 1);
        atomicAdd(&hist[dv.w >> BINSH], 1);
    } else {
        for (int k = 0; k < 4; ++k)
            if (e0 + e + k < N_EDGES) atomicAdd(&hist[dst[e0 + e + k] >> BINSH], 1);
    }
    __syncthreads();
    int v = (t < NBIN) ? hist[t] : 0;
    int x = v;
#pragma unroll
    for (int d = 1; d < 64; d <<= 1) {
        int y = __shfl_up(x, d, 64);
        if ((t & 63) >= d) x += y;
    }
    if ((t & 63) == 63) wpart[t >> 6] = x;
    __syncthreads();
    if (t == 0) {
        int a = 0;
        for (int w = 0; w < 8; ++w) { int q = wpart[w]; wpart[w] = a; a += q; }
    }
    __syncthreads();
    int excl = x - v + wpart[t >> 6];
    if (t < NBIN) { lexcl[t] = excl; lcur[t] = excl; }
    __syncthreads();
    if (t < NBIN && v > 0) runbase[t] = atomicAdd(&gbin_cursor[t], v);
    if (t < N_GRAPHS && gh[t]) atomicAdd(&cnt[t], gh[t]);
    __syncthreads();
    if (full) {
        int p;
        p = atomicAdd(&lcur[dv.x >> BINSH], 1); stage[p] = make_int2(sv.x, dv.x);
        p = atomicAdd(&lcur[dv.y >> BINSH], 1); stage[p] = make_int2(sv.y, dv.y);
        p = atomicAdd(&lcur[dv.z >> BINSH], 1); stage[p] = make_int2(sv.z, dv.z);
        p = atomicAdd(&lcur[dv.w >> BINSH], 1); stage[p] = make_int2(sv.w, dv.w);
    } else {
        for (int k = 0; k < 4; ++k) {
            if (e0 + e + k < N_EDGES) {
                int d = dst[e0 + e + k];
                int p = atomicAdd(&lcur[d >> BINSH], 1);
                stage[p] = make_int2(src[e0 + e + k], d);
            }
        }
    }
    __syncthreads();
    int m = N_EDGES - e0;
    if (m > EPB) m = EPB;
    for (int i = 4 * t; i < 4 * t + 4 && i < m; ++i) {
        int2 pr = stage[i];
        int b = pr.y >> BINSH;
        binned[(size_t)b * BINCAP + runbase[b] + (i - lexcl[b])] = pr;
    }
}

// ---- Pass B: counting sort -> off/csr, FUSED with layer 1 (edge-parallel
// LDS-atomic rank-1 GAT) and fp32 attention logits (a_src2/a_dst2 via the
// reassociated small GEMM h1a @ Ws, Ws[k][h] = sum_c W2[k][h*16+c]*as2[h,c]).
__global__ __launch_bounds__(1024) void k_binB(
    const int2* __restrict__ binned, const int* __restrict__ gbin_cursor,
    int* __restrict__ off, int* __restrict__ csr,
    const float* __restrict__ x, const float* __restrict__ W1,
    const float* __restrict__ as1, const float* __restrict__ ad1,
    const float* __restrict__ b1, const float* __restrict__ W2,
    const float* __restrict__ as2, const float* __restrict__ ad2,
    float* __restrict__ s1, float2* __restrict__ ap, float2* __restrict__ dp) {
    __shared__ int hist[256];
    __shared__ int wpart[4];
    __shared__ int s_ebase;
    __shared__ float xb[256];
    __shared__ float smW1[64], smB1[64];
    __shared__ float ws8[8], wd8[8];
    __shared__ float Wsm[64 * 8], Wdm[64 * 8];
    __shared__ float lnum[256 * 8], lden[256 * 8];
    __shared__ float s1l[256 * 8];
    int b = blockIdx.x, t = threadIdx.x;
    int count = gbin_cursor[b];
    int node0 = b << BINSH;
    const int2* my = binned + (size_t)b * BINCAP;

    // ---- P0: zero + stage
    if (t == 0) s_ebase = 0;
    if (t < 256) {
        hist[t] = 0;
        int n = node0 + t;
        xb[t] = (n < N_NODES) ? x[n] : 0.f;
    }
    if (t < 64) { smW1[t] = W1[t]; smB1[t] = b1[t]; }
    for (int i = t; i < 2048; i += 1024) { lnum[i] = 0.f; lden[i] = 0.f; }
    if (t >= 64 && t < 72) {  // ws1/wd1 rank-1 precompute
        int h = t - 64;
        float s = 0.f, d = 0.f;
        for (int c = 0; c < 8; ++c) {
            float w = W1[h * 8 + c];
            s += w * as1[h * 8 + c];
            d += w * ad1[h * 8 + c];
        }
        ws8[h] = s;
        wd8[h] = d;
    }
    {   // Ws / Wd: 512 entries each, 16-length dots
        int tt = t & 511;
        int k = tt >> 3, h = tt & 7;
        float acc = 0.f;
        const float* att = (t < 512) ? as2 : ad2;
        for (int c = 0; c < 16; ++c)
            acc += W2[k * 128 + h * 16 + c] * att[h * 16 + c];
        if (t < 512) Wsm[k * 8 + h] = acc; else Wdm[k * 8 + h] = acc;
    }
    __syncthreads();

    // ---- P1: ebase partial + histogram
    if (t < b) atomicAdd(&s_ebase, gbin_cursor[t]);
    for (int i = t; i < count; i += 1024) atomicAdd(&hist[my[i].y - node0], 1);
    __syncthreads();

    // ---- P2: 2-barrier scan over 256 keys
    int v = (t < 256) ? hist[t] : 0;
    int xx = v;
#pragma unroll
    for (int d = 1; d < 64; d <<= 1) {
        int y = __shfl_up(xx, d, 64);
        if ((t & 63) >= d) xx += y;
    }
    if (t < 256 && (t & 63) == 63) wpart[t >> 6] = xx;
    __syncthreads();
    if (t == 0) {
        int a = 0;
        for (int w = 0; w < 4; ++w) { int q = wpart[w]; wpart[w] = a; a += q; }
    }
    __syncthreads();
    int ebase = s_ebase;
    int excl = xx - v + ((t < 256) ? wpart[t >> 6] : 0);
    if (t < 256) {
        int n = node0 + t;
        if (n < N_NODES) off[n] = ebase + excl;
    }
    if (b == 0 && t == 0) off[N_NODES] = N_EDGES;
    __syncthreads();
    if (t < 256) hist[t] = excl;  // local cursor
    __syncthreads();

    // ---- P3: csr fill + layer-1 edge accumulation (LDS atomics)
    for (int i = t; i < count; i += 1024) {
        int2 pr = my[i];
        int dloc = pr.y - node0;
        int p = atomicAdd(&hist[dloc], 1);
        csr[ebase + p] = pr.x;
        float xs = x[pr.x];
        float xn = xb[dloc];
#pragma unroll
        for (int h = 0; h < 8; ++h) {
            float w = __expf(lrelu(xs * ws8[h] + xn * wd8[h]));
            atomicAdd(&lden[dloc * 8 + h], w);
            atomicAdd(&lnum[dloc * 8 + h], w * xs);
        }
    }
    __syncthreads();

    // ---- P4: finalize s1 (self loop + divide)
    if (t < 256) {
        int n = node0 + t;
        if (n < N_NODES) {
            float xn = xb[t];
#pragma unroll
            for (int h = 0; h < 8; ++h) {
                float w = __expf(lrelu(xn * ws8[h] + xn * wd8[h]));
                float num = lnum[t * 8 + h] + w * xn;
                float den = lden[t * 8 + h] + w;
                float vv = num / den;
                s1l[t * 8 + h] = vv;
                s1[n * 8 + h] = vv;
            }
        }
    }
    __syncthreads();

    // ---- P5: fp32 attention logits. 4 lanes/node; lane j -> heads j, j+4.
    {
        int nl = t >> 2, j = t & 3;
        int n = node0 + nl;
        if (n < N_NODES) {
            float pSA = 0.f, pSB = 0.f, pDA = 0.f, pDB = 0.f;
#pragma unroll 8
            for (int k = 0; k < 64; ++k) {
                float h1a = elu_f(s1l[nl * 8 + (k >> 3)] * smW1[k] + smB1[k]);
                pSA += h1a * Wsm[k * 8 + j];
                pSB += h1a * Wsm[k * 8 + j + 4];
                pDA += h1a * Wdm[k * 8 + j];
                pDB += h1a * Wdm[k * 8 + j + 4];
            }
            ap[n * 4 + j] = make_float2(pSA, pSB);
            dp[n * 4 + j] = make_float2(pDA, pDB);
        }
    }
}

// ---- MFMA message GEMM: h2[NPAD,128] = elu(h1)@W2, fp16 in / fp32 acc.
// 64 nodes/block, 16 nodes/wave; per wave: 16 mfma_f32_16x16x32_f16.
// A frag: A[m=lane&15][k=quad*8+j]; B frag: B[k=quad*8+j][n=lane&15];
// D: col=lane&15, row=quad*4+reg (m89/m120-verified layouts).
__global__ __launch_bounds__(256) void k_gemm(
    const float* __restrict__ s1, const float* __restrict__ W1,
    const float* __restrict__ b1, const float* __restrict__ W2,
    __half2* __restrict__ h2p) {
    __shared__ _Float16 smWT[128 * 72];  // W2^T, padded (+8) halves per row
    __shared__ _Float16 smA[64 * 72];    // h1a for 64 nodes, padded
    int t = threadIdx.x;
    int nblk = blockIdx.x * 64;
    // stage W2^T as fp16
    for (int idx = t; idx < 128 * 64; idx += 256) {
        int c = idx >> 6, k = idx & 63;
        smWT[c * 72 + k] = (_Float16)W2[k * 128 + c];
    }
    // stage A: h1a = elu(s1*W1+b1), 4 threads/node x 16 k each
    {
        int m = t >> 2, kb = (t & 3) * 16;
        int n = nblk + m;                 // grid exact: 1563*64 == NPAD
        float sv0 = s1[n * 8 + (kb >> 3)];
        float sv1 = s1[n * 8 + (kb >> 3) + 1];
#pragma unroll
        for (int kk = 0; kk < 16; ++kk) {
            int k = kb + kk;
            float a = (kk < 8 ? sv0 : sv1) * W1[k] + b1[k];
            smA[m * 72 + k] = (_Float16)elu_f(a);
        }
    }
    __syncthreads();

    int lane = t & 63, wave = t >> 6;
    int quad = lane >> 4, m15 = lane & 15;
    half8 a0 = *reinterpret_cast<const half8*>(&smA[(wave * 16 + m15) * 72 + quad * 8]);
    half8 a1 = *reinterpret_cast<const half8*>(&smA[(wave * 16 + m15) * 72 + 32 + quad * 8]);
    float4v acc[8];
#pragma unroll
    for (int tl = 0; tl < 8; ++tl) {
        half8 b0 = *reinterpret_cast<const half8*>(&smWT[(tl * 16 + m15) * 72 + quad * 8]);
        half8 b1v = *reinterpret_cast<const half8*>(&smWT[(tl * 16 + m15) * 72 + 32 + quad * 8]);
        float4v c = {0.f, 0.f, 0.f, 0.f};
        c = __builtin_amdgcn_mfma_f32_16x16x32_f16(a0, b0, c, 0, 0, 0);
        c = __builtin_amdgcn_mfma_f32_16x16x32_f16(a1, b1v, c, 0, 0, 0);
        acc[tl] = c;
    }
    // store packed: h2p[n*64 + 16*tl + m15] = {col, col+64}
#pragma unroll
    for (int tl = 0; tl < 4; ++tl) {
#pragma unroll
        for (int reg = 0; reg < 4; ++reg) {
            int n = nblk + wave * 16 + quad * 4 + reg;
            if (n < N_NODES)
                h2p[n * 64 + tl * 16 + m15] =
                    __floats2half2_rn(acc[tl][reg], acc[tl + 4][reg]);
        }
    }
}

// ---- Layer 2 aggregation: frozen at the R10 structure (~110us, pinned by
// the random-gather path at ~2.4 TB/s).
__global__ __launch_bounds__(256, 8) void k_layer2(
    const __half2* __restrict__ h2p, const float2* __restrict__ ap,
    const float2* __restrict__ dp, const int* __restrict__ off,
    const int* __restrict__ csr, const int* __restrict__ batch,
    float* __restrict__ pool) {
    __shared__ float smv[4][16];
    __shared__ int smg[4];
    const float* apf = (const float*)ap;   // flat: node*8 + 2*(h&3) + (h>>2)
    const float* dpf = (const float*)dp;
    int t = threadIdx.x;
    int wid = t >> 6, l = t & 63;
    int n = blockIdx.x * 4 + wid;  // grid exact: 25000*4 == N_NODES
    int hA = l >> 4;               // channel-group head
    int hh = l & 7;                // weight-phase head
    int j8 = l >> 3;               // weight-phase edge slot
    int fidx = 2 * (hh & 3) + (hh >> 2);
    float dn = dpf[n * 8 + fidx];  // adst[n][hh]

    float2 ad = dp[n * 4 + hA];
    float2 an = ap[n * 4 + hA];
    float wA = __expf(lrelu(an.x + ad.x));
    float wB = __expf(lrelu(an.y + ad.y));
    float2 hn = __half22float2(h2p[n * 64 + l]);
    float accA = wA * hn.x, accB = wB * hn.y;
    float denTA = wA, denTB = wB;
    float wsum = 0.f;

    int b = off[n];
    int deg = off[n + 1] - b;
    for (int base = 0; base < deg; base += 64) {
        int rem = deg - base;
        if (rem > 64) rem = 64;
        int sl = (l < rem) ? csr[b + base + l] : 0;
        int g = 0;
        for (; g + 8 <= rem; g += 8) {
            int sg = __shfl(sl, g + j8, 64);
            float w = __expf(lrelu(apf[sg * 8 + fidx] + dn));
            wsum += w;
#pragma unroll
            for (int j2 = 0; j2 < 8; ++j2) {
                int s = __builtin_amdgcn_readlane(sl, g + j2);
                float wa = __shfl(w, j2 * 8 + hA, 64);
                float wb = __shfl(w, j2 * 8 + hA + 4, 64);
                float2 gg = __half22float2(h2p[s * 64 + l]);
                accA = fmaf(wa, gg.x, accA);
                accB = fmaf(wb, gg.y, accB);
            }
        }
        if (g < rem) {
            int cnt = rem - g;
            int jj = (j8 < cnt) ? j8 : 0;
            int sg = __shfl(sl, g + jj, 64);
            float w = (j8 < cnt) ? __expf(lrelu(apf[sg * 8 + fidx] + dn)) : 0.f;
            wsum += w;
            for (int j2 = 0; j2 < cnt; ++j2) {
                int s = __builtin_amdgcn_readlane(sl, g + j2);
                float wa = __shfl(w, j2 * 8 + hA, 64);
                float wb = __shfl(w, j2 * 8 + hA + 4, 64);
                float2 gg = __half22float2(h2p[s * 64 + l]);
                accA = fmaf(wa, gg.x, accA);
                accB = fmaf(wb, gg.y, accB);
            }
        }
    }
    wsum += __shfl_xor(wsum, 8, 64);
    wsum += __shfl_xor(wsum, 16, 64);
    wsum += __shfl_xor(wsum, 32, 64);
    float denA = denTA + __shfl(wsum, hA, 64);
    float denB = denTB + __shfl(wsum, hA + 4, 64);

    float v = accA / denA + accB / denB;
    v += __shfl_xor(v, 16, 64);
    v += __shfl_xor(v, 32, 64);
    v *= 0.125f;  // mean over 8 heads
    if (l < 16) smv[wid][l] = v;
    if (l == 0) smg[wid] = batch[n];
    __syncthreads();
    if (t < 64) {
        int w = t >> 4, c = t & 15;
        int g = smg[w];
        bool leader = true;
        for (int w2 = 0; w2 < w; ++w2)
            if (smg[w2] == g) { leader = false; break; }
        if (leader) {
            float s = smv[w][c];
            for (int w2 = w + 1; w2 < 4; ++w2)
                if (smg[w2] == g) s += smv[w2][c];
            atomicAdd(&pool[g * 16 + c], s);
        }
    }
}

// ---- final: pooled mean (+b2) @ Wfc + bfc -> [64,4]
__global__ void k_final(const float* __restrict__ pool, const int* __restrict__ cnt,
                        const float* __restrict__ b2, const float* __restrict__ Wfc,
                        const float* __restrict__ bfc, float* __restrict__ out) {
    int t = threadIdx.x;
    int g = t >> 2, k = t & 3;
    float c = (float)(cnt[g] > 0 ? cnt[g] : 1);
    float acc = bfc[k];
#pragma unroll
    for (int ci = 0; ci < 16; ++ci)
        acc += (pool[g * 16 + ci] / c + b2[ci]) * Wfc[ci * 4 + k];
    out[g * 4 + k] = acc;
}

extern "C" void kernel_launch(void* const* d_in, const int* in_sizes, int n_in,
                              void* d_out, int out_size, void* d_ws, size_t ws_size,
                              hipStream_t stream) {
    const float* x   = (const float*)d_in[0];
    const float* W1  = (const float*)d_in[1];
    const float* as1 = (const float*)d_in[2];
    const float* ad1 = (const float*)d_in[3];
    const float* b1  = (const float*)d_in[4];
    const float* W2  = (const float*)d_in[5];
    const float* as2 = (const float*)d_in[6];
    const float* ad2 = (const float*)d_in[7];
    const float* b2  = (const float*)d_in[8];
    const float* Wfc = (const float*)d_in[9];
    const float* bfc = (const float*)d_in[10];
    const int* ei    = (const int*)d_in[11];
    const int* batch = (const int*)d_in[12];
    const int* srcv  = ei;             // edge_index[0]
    const int* dstv  = ei + N_EDGES;   // edge_index[1]

    char* ws = (char*)d_ws;
    size_t o = 0;
    auto alloc = [&](size_t bytes) {
        void* p = ws + o;
        o += (bytes + 255) & ~(size_t)255;
        return p;
    };
    // zero-region first (one memset): cnt, pool, gbin_cursor
    int*    cnt     = (int*)alloc(64 * 4);
    float*  pool    = (float*)alloc(64 * 16 * 4);
    int*    gbin    = (int*)alloc(NBIN * 4);
    size_t  zbytes  = o;
    int*    off     = (int*)alloc((size_t)(N_NODES + 1) * 4);
    int*    csr     = (int*)alloc((size_t)N_EDGES * 4);
    float*  s1      = (float*)alloc((size_t)NPAD * 8 * 4);       // padded for gemm grid
    float2* ap      = (float2*)alloc((size_t)N_NODES * 4 * 8);
    float2* dp      = (float2*)alloc((size_t)N_NODES * 4 * 8);
    // union: binned (CSR build) aliases h2p (gemm onward); ap/dp now separate
    size_t  ub      = (size_t)392 * BINCAP * 8;                  // 19.3 MB
    size_t  hb      = (size_t)N_NODES * 64 * 4;                  // 25.6 MB
    char*   ubase   = (char*)alloc(ub > hb ? ub : hb);
    int2*   binned  = (int2*)ubase;
    __half2* h2p    = (__half2*)ubase;

    hipMemsetAsync(d_ws, 0, zbytes, stream);

    int nbA = (N_EDGES + EPB - 1) / EPB;   // 782

    k_binA<<<nbA, 512, 0, stream>>>(srcv, dstv, batch, gbin, cnt, binned);
    k_binB<<<NBIN, 1024, 0, stream>>>(binned, gbin, off, csr,
                                      x, W1, as1, ad1, b1, W2, as2, ad2,
                                      s1, ap, dp);
    k_gemm<<<NPAD / 64, 256, 0, stream>>>(s1, W1, b1, W2, h2p);
    k_layer2<<<N_NODES / 4, 256, 0, stream>>>(h2p, ap, dp, off, csr, batch, pool);
    k_final<<<1, 256, 0, stream>>>(pool, cnt, b2, Wfc, bfc, (float*)d_out);
}

// Round 14
// 324.439 us; speedup vs baseline: 1.3564x; 1.3564x over previous
//
#include <hip/hip_runtime.h>
#include <hip/hip_fp16.h>

#define N_NODES  100000
#define NPAD     100032     // 1563*64, gemm grid padding
#define N_EDGES  1600000
#define N_GRAPHS 64

#define BINSH  8
#define NBIN   392          // ceil(100000 / 256)
#define BINCAP 6144         // Poisson(4096) max ~4.5K; 1.5x headroom
#define EPB    2048         // edges per block in k_binA

typedef _Float16 half8 __attribute__((ext_vector_type(8)));
typedef float float4v __attribute__((ext_vector_type(4)));

__device__ __forceinline__ float lrelu(float v) { return v > 0.f ? v : 0.2f * v; }
__device__ __forceinline__ float elu_f(float v) { return v > 0.f ? v : __expf(v) - 1.f; }

// ---- Pass A: coarse-bin edges (dst>>8) into per-bin regions, coalesced runs.
__global__ __launch_bounds__(512) void k_binA(
    const int* __restrict__ src, const int* __restrict__ dst,
    const int* __restrict__ batch, int* __restrict__ gbin_cursor,
    int* __restrict__ cnt, int2* __restrict__ binned) {
    __shared__ int hist[NBIN], lexcl[NBIN], runbase[NBIN], lcur[NBIN];
    __shared__ int wpart[8];
    __shared__ int gh[N_GRAPHS];
    __shared__ int2 stage[EPB];
    int t = threadIdx.x;
    int e0 = blockIdx.x * EPB;
    for (int b = t; b < NBIN; b += 512) hist[b] = 0;
    if (t < N_GRAPHS) gh[t] = 0;
    __syncthreads();
    int nid = blockIdx.x * 512 + t;   // 782*512 >= N_NODES
    if (nid < N_NODES) atomicAdd(&gh[batch[nid]], 1);
    int e = 4 * t;                    // block-local edge base
    int4 dv = make_int4(0, 0, 0, 0), sv = make_int4(0, 0, 0, 0);
    bool full = (e0 + e + 3 < N_EDGES);
    if (full) {
        dv = *(const int4*)(dst + e0 + e);
        sv = *(const int4*)(src + e0 + e);
        atomicAdd(&hist[dv.x >> BINSH], 1);
        atomicAdd(&hist[dv.y >> BINSH], 1);
        atomicAdd(&hist[dv.z >> BINSH], 1);
        atomicAdd(&hist[dv.w >> BINSH], 1);
    } else {
        for (int k = 0; k < 4; ++k)
            if (e0 + e + k < N_EDGES) atomicAdd(&hist[dst[e0 + e + k] >> BINSH], 1);
    }
    __syncthreads();
    int v = (t < NBIN) ? hist[t] : 0;
    int x = v;
#pragma unroll
    for (int d = 1; d < 64; d <<= 1) {
        int y = __shfl_up(x, d, 64);
        if ((t & 63) >= d) x += y;
    }
    if ((t & 63) == 63) wpart[t >> 6] = x;
    __syncthreads();
    if (t == 0) {
        int a = 0;
        for (int w = 0; w < 8; ++w) { int q = wpart[w]; wpart[w] = a; a += q; }
    }
    __syncthreads();
    int excl = x - v + wpart[t >> 6];
    if (t < NBIN) { lexcl[t] = excl; lcur[t] = excl; }
    __syncthreads();
    if (t < NBIN && v > 0) runbase[t] = atomicAdd(&gbin_cursor[t], v);
    if (t < N_GRAPHS && gh[t]) atomicAdd(&cnt[t], gh[t]);
    __syncthreads();
    if (full) {
        int p;
        p = atomicAdd(&lcur[dv.x >> BINSH], 1); stage[p] = make_int2(sv.x, dv.x);
        p = atomicAdd(&lcur[dv.y >> BINSH], 1); stage[p] = make_int2(sv.y, dv.y);
        p = atomicAdd(&lcur[dv.z >> BINSH], 1); stage[p] = make_int2(sv.z, dv.z);
        p = atomicAdd(&lcur[dv.w >> BINSH], 1); stage[p] = make_int2(sv.w, dv.w);
    } else {
        for (int k = 0; k < 4; ++k) {
            if (e0 + e + k < N_EDGES) {
                int d = dst[e0 + e + k];
                int p = atomicAdd(&lcur[d >> BINSH], 1);
                stage[p] = make_int2(src[e0 + e + k], d);
            }
        }
    }
    __syncthreads();
    int m = N_EDGES - e0;
    if (m > EPB) m = EPB;
    for (int i = 4 * t; i < 4 * t + 4 && i < m; ++i) {
        int2 pr = stage[i];
        int b = pr.y >> BINSH;
        binned[(size_t)b * BINCAP + runbase[b] + (i - lexcl[b])] = pr;
    }
}

// ---- Pass B: R12-style counting sort -> off/csr (NO layer-1 fusion — the
// R13 LDS-atomic variant hit 511K bank conflicts / 196us). Block 0 also
// computes the exact-fp32 logit matrices into prep:
// prep[0..511]=Ws[k][h], [512..1023]=Wd[k][h], [1024..1031]=ws8, [1032..1039]=wd8.
__global__ __launch_bounds__(1024) void k_binB(
    const int2* __restrict__ binned, const int* __restrict__ gbin_cursor,
    int* __restrict__ off, int* __restrict__ csr,
    const float* __restrict__ W1, const float* __restrict__ as1,
    const float* __restrict__ ad1, const float* __restrict__ W2,
    const float* __restrict__ as2, const float* __restrict__ ad2,
    float* __restrict__ prep) {
    __shared__ int hist[256];
    __shared__ int wpart[4];
    __shared__ int s_ebase;
    int b = blockIdx.x, t = threadIdx.x;
    int count = gbin_cursor[b];
    int node0 = b << BINSH;
    const int2* my = binned + (size_t)b * BINCAP;
    if (t == 0) s_ebase = 0;
    if (t < 256) hist[t] = 0;
    __syncthreads();
    if (t < b) atomicAdd(&s_ebase, gbin_cursor[t]);
    for (int i = t; i < count; i += 1024) atomicAdd(&hist[my[i].y - node0], 1);
    __syncthreads();
    int v = (t < 256) ? hist[t] : 0;
    int x = v;
#pragma unroll
    for (int d = 1; d < 64; d <<= 1) {
        int y = __shfl_up(x, d, 64);
        if ((t & 63) >= d) x += y;
    }
    if (t < 256 && (t & 63) == 63) wpart[t >> 6] = x;
    __syncthreads();
    if (t == 0) {
        int a = 0;
        for (int w = 0; w < 4; ++w) { int q = wpart[w]; wpart[w] = a; a += q; }
    }
    __syncthreads();
    int ebase = s_ebase;
    int excl = x - v + ((t < 256) ? wpart[t >> 6] : 0);
    if (t < 256) {
        int n = node0 + t;
        if (n < N_NODES) off[n] = ebase + excl;
    }
    if (b == 0 && t == 0) off[N_NODES] = N_EDGES;
    __syncthreads();
    if (t < 256) hist[t] = excl;  // becomes the local cursor
    __syncthreads();
    for (int i = t; i < count; i += 1024) {
        int2 pr = my[i];
        int p = atomicAdd(&hist[pr.y - node0], 1);
        csr[ebase + p] = pr.x;
    }
    // ---- block 0: prep (independent of the sort; W2 read exactly once)
    if (b == 0) {
        int tt = t & 511;
        int k = tt >> 3, h = tt & 7;
        const float* att = (t < 512) ? as2 : ad2;
        float acc = 0.f;
        for (int c = 0; c < 16; ++c)
            acc += W2[k * 128 + h * 16 + c] * att[h * 16 + c];
        prep[t] = acc;
        if (t < 8) {
            float s = 0.f, d = 0.f;
            for (int c = 0; c < 8; ++c) {
                float w = W1[t * 8 + c];
                s += w * as1[t * 8 + c];
                d += w * ad1[t * 8 + c];
            }
            prep[1024 + t] = s;
            prep[1032 + t] = d;
        }
    }
}

// ---- Layer 1 + exact-fp32 logits. 16 nodes/block, 16 lanes/node.
// Phase 1: rank-1 GAT shuffle-reduce (no atomics) -> s1 global + LDS.
// Phase 2: a_src2/a_dst2 = h1a @ Ws/Wd (lane c covers k=4c..4c+3).
__global__ __launch_bounds__(256) void k_layer1(
    const float* __restrict__ x, const float* __restrict__ W1,
    const float* __restrict__ b1, const float* __restrict__ prep,
    const int* __restrict__ off, const int* __restrict__ csr,
    float* __restrict__ s1, float2* __restrict__ ap, float2* __restrict__ dp) {
    __shared__ float smS1[16][8];
    __shared__ float smWs[512], smWd[512];
    __shared__ float smW1[64], smB1[64];
    __shared__ float ws8s[8], wd8s[8];
    int t = threadIdx.x;
    for (int i = t; i < 512; i += 256) { smWs[i] = prep[i]; smWd[i] = prep[512 + i]; }
    if (t < 64) { smW1[t] = W1[t]; smB1[t] = b1[t]; }
    if (t < 8) { ws8s[t] = prep[1024 + t]; wd8s[t] = prep[1032 + t]; }
    __syncthreads();
    int nl = t >> 4, c = t & 15;
    int n = blockIdx.x * 16 + nl;   // grid exact: 6250*16 == N_NODES
    // ---- phase 1
    {
        float ws[8], wd[8];
#pragma unroll
        for (int h = 0; h < 8; ++h) { ws[h] = ws8s[h]; wd[h] = wd8s[h]; }
        float xn = x[n];
        float num[8], den[8];
#pragma unroll
        for (int h = 0; h < 8; ++h) { num[h] = 0.f; den[h] = 0.f; }
        if (c == 0) {  // self loop
#pragma unroll
            for (int h = 0; h < 8; ++h) {
                float w = __expf(lrelu(xn * ws[h] + xn * wd[h]));
                den[h] = w;
                num[h] = w * xn;
            }
        }
        int b = off[n], e = off[n + 1];
        for (int i = b + c; i < e; i += 16) {
            int s = csr[i];
            float xs = x[s];
#pragma unroll
            for (int h = 0; h < 8; ++h) {
                float w = __expf(lrelu(xs * ws[h] + xn * wd[h]));
                den[h] += w;
                num[h] += w * xs;
            }
        }
#pragma unroll
        for (int d = 1; d < 16; d <<= 1) {
#pragma unroll
            for (int h = 0; h < 8; ++h) {
                num[h] += __shfl_xor(num[h], d, 64);
                den[h] += __shfl_xor(den[h], d, 64);
            }
        }
        if (c == 0) {
#pragma unroll
            for (int h = 0; h < 8; ++h) {
                float vv = num[h] / den[h];
                smS1[nl][h] = vv;
                s1[n * 8 + h] = vv;
            }
        }
    }
    __syncthreads();
    // ---- phase 2: logits (exact fp32)
    float pS[8], pD[8];
#pragma unroll
    for (int h = 0; h < 8; ++h) { pS[h] = 0.f; pD[h] = 0.f; }
#pragma unroll
    for (int kk = 0; kk < 4; ++kk) {
        int k = c * 4 + kk;
        float h1a = elu_f(smS1[nl][k >> 3] * smW1[k] + smB1[k]);
#pragma unroll
        for (int h = 0; h < 8; ++h) {
            pS[h] = fmaf(h1a, smWs[k * 8 + h], pS[h]);
            pD[h] = fmaf(h1a, smWd[k * 8 + h], pD[h]);
        }
    }
#pragma unroll
    for (int d = 1; d < 16; d <<= 1) {
#pragma unroll
        for (int h = 0; h < 8; ++h) {
            pS[h] += __shfl_xor(pS[h], d, 64);
            pD[h] += __shfl_xor(pD[h], d, 64);
        }
    }
    if (c == 0) {
#pragma unroll
        for (int h = 0; h < 4; ++h) {
            ap[n * 4 + h] = make_float2(pS[h], pS[h + 4]);
            dp[n * 4 + h] = make_float2(pD[h], pD[h + 4]);
        }
    }
}

// ---- MFMA message GEMM: h2[NPAD,128] = elu(h1)@W2, fp16 in / fp32 acc.
// 64 nodes/block, 16 nodes/wave; per wave: 16 mfma_f32_16x16x32_f16.
// (R13-verified: passed with absmax 6.1e-5.)
__global__ __launch_bounds__(256) void k_gemm(
    const float* __restrict__ s1, const float* __restrict__ W1,
    const float* __restrict__ b1, const float* __restrict__ W2,
    __half2* __restrict__ h2p) {
    __shared__ _Float16 smWT[128 * 72];  // W2^T, padded (+8) halves per row
    __shared__ _Float16 smA[64 * 72];    // h1a for 64 nodes, padded
    int t = threadIdx.x;
    int nblk = blockIdx.x * 64;
    for (int idx = t; idx < 128 * 64; idx += 256) {
        int c = idx >> 6, k = idx & 63;
        smWT[c * 72 + k] = (_Float16)W2[k * 128 + c];
    }
    {
        int m = t >> 2, kb = (t & 3) * 16;
        int n = nblk + m;                 // grid exact: 1563*64 == NPAD
        float sv0 = s1[n * 8 + (kb >> 3)];
        float sv1 = s1[n * 8 + (kb >> 3) + 1];
#pragma unroll
        for (int kk = 0; kk < 16; ++kk) {
            int k = kb + kk;
            float a = (kk < 8 ? sv0 : sv1) * W1[k] + b1[k];
            smA[m * 72 + k] = (_Float16)elu_f(a);
        }
    }
    __syncthreads();

    int lane = t & 63, wave = t >> 6;
    int quad = lane >> 4, m15 = lane & 15;
    half8 a0 = *reinterpret_cast<const half8*>(&smA[(wave * 16 + m15) * 72 + quad * 8]);
    half8 a1 = *reinterpret_cast<const half8*>(&smA[(wave * 16 + m15) * 72 + 32 + quad * 8]);
    float4v acc[8];
#pragma unroll
    for (int tl = 0; tl < 8; ++tl) {
        half8 b0 = *reinterpret_cast<const half8*>(&smWT[(tl * 16 + m15) * 72 + quad * 8]);
        half8 b1v = *reinterpret_cast<const half8*>(&smWT[(tl * 16 + m15) * 72 + 32 + quad * 8]);
        float4v c = {0.f, 0.f, 0.f, 0.f};
        c = __builtin_amdgcn_mfma_f32_16x16x32_f16(a0, b0, c, 0, 0, 0);
        c = __builtin_amdgcn_mfma_f32_16x16x32_f16(a1, b1v, c, 0, 0, 0);
        acc[tl] = c;
    }
#pragma unroll
    for (int tl = 0; tl < 4; ++tl) {
#pragma unroll
        for (int reg = 0; reg < 4; ++reg) {
            int n = nblk + wave * 16 + quad * 4 + reg;
            if (n < N_NODES)
                h2p[n * 64 + tl * 16 + m15] =
                    __floats2half2_rn(acc[tl][reg], acc[tl + 4][reg]);
        }
    }
}

// ---- Layer 2 aggregation: frozen at the R10 structure (~110us, pinned by
// the random-gather path at ~2.4 TB/s).
__global__ __launch_bounds__(256, 8) void k_layer2(
    const __half2* __restrict__ h2p, const float2* __restrict__ ap,
    const float2* __restrict__ dp, const int* __restrict__ off,
    const int* __restrict__ csr, const int* __restrict__ batch,
    float* __restrict__ pool) {
    __shared__ float smv[4][16];
    __shared__ int smg[4];
    const float* apf = (const float*)ap;   // flat: node*8 + 2*(h&3) + (h>>2)
    const float* dpf = (const float*)dp;
    int t = threadIdx.x;
    int wid = t >> 6, l = t & 63;
    int n = blockIdx.x * 4 + wid;  // grid exact: 25000*4 == N_NODES
    int hA = l >> 4;               // channel-group head
    int hh = l & 7;                // weight-phase head
    int j8 = l >> 3;               // weight-phase edge slot
    int fidx = 2 * (hh & 3) + (hh >> 2);
    float dn = dpf[n * 8 + fidx];  // adst[n][hh]

    float2 ad = dp[n * 4 + hA];
    float2 an = ap[n * 4 + hA];
    float wA = __expf(lrelu(an.x + ad.x));
    float wB = __expf(lrelu(an.y + ad.y));
    float2 hn = __half22float2(h2p[n * 64 + l]);
    float accA = wA * hn.x, accB = wB * hn.y;
    float denTA = wA, denTB = wB;
    float wsum = 0.f;

    int b = off[n];
    int deg = off[n + 1] - b;
    for (int base = 0; base < deg; base += 64) {
        int rem = deg - base;
        if (rem > 64) rem = 64;
        int sl = (l < rem) ? csr[b + base + l] : 0;
        int g = 0;
        for (; g + 8 <= rem; g += 8) {
            int sg = __shfl(sl, g + j8, 64);
            float w = __expf(lrelu(apf[sg * 8 + fidx] + dn));
            wsum += w;
#pragma unroll
            for (int j2 = 0; j2 < 8; ++j2) {
                int s = __builtin_amdgcn_readlane(sl, g + j2);
                float wa = __shfl(w, j2 * 8 + hA, 64);
                float wb = __shfl(w, j2 * 8 + hA + 4, 64);
                float2 gg = __half22float2(h2p[s * 64 + l]);
                accA = fmaf(wa, gg.x, accA);
                accB = fmaf(wb, gg.y, accB);
            }
        }
        if (g < rem) {
            int cnt = rem - g;
            int jj = (j8 < cnt) ? j8 : 0;
            int sg = __shfl(sl, g + jj, 64);
            float w = (j8 < cnt) ? __expf(lrelu(apf[sg * 8 + fidx] + dn)) : 0.f;
            wsum += w;
            for (int j2 = 0; j2 < cnt; ++j2) {
                int s = __builtin_amdgcn_readlane(sl, g + j2);
                float wa = __shfl(w, j2 * 8 + hA, 64);
                float wb = __shfl(w, j2 * 8 + hA + 4, 64);
                float2 gg = __half22float2(h2p[s * 64 + l]);
                accA = fmaf(wa, gg.x, accA);
                accB = fmaf(wb, gg.y, accB);
            }
        }
    }
    wsum += __shfl_xor(wsum, 8, 64);
    wsum += __shfl_xor(wsum, 16, 64);
    wsum += __shfl_xor(wsum, 32, 64);
    float denA = denTA + __shfl(wsum, hA, 64);
    float denB = denTB + __shfl(wsum, hA + 4, 64);

    float v = accA / denA + accB / denB;
    v += __shfl_xor(v, 16, 64);
    v += __shfl_xor(v, 32, 64);
    v *= 0.125f;  // mean over 8 heads
    if (l < 16) smv[wid][l] = v;
    if (l == 0) smg[wid] = batch[n];
    __syncthreads();
    if (t < 64) {
        int w = t >> 4, c = t & 15;
        int g = smg[w];
        bool leader = true;
        for (int w2 = 0; w2 < w; ++w2)
            if (smg[w2] == g) { leader = false; break; }
        if (leader) {
            float s = smv[w][c];
            for (int w2 = w + 1; w2 < 4; ++w2)
                if (smg[w2] == g) s += smv[w2][c];
            atomicAdd(&pool[g * 16 + c], s);
        }
    }
}

// ---- final: pooled mean (+b2) @ Wfc + bfc -> [64,4]
__global__ void k_final(const float* __restrict__ pool, const int* __restrict__ cnt,
                        const float* __restrict__ b2, const float* __restrict__ Wfc,
                        const float* __restrict__ bfc, float* __restrict__ out) {
    int t = threadIdx.x;
    int g = t >> 2, k = t & 3;
    float c = (float)(cnt[g] > 0 ? cnt[g] : 1);
    float acc = bfc[k];
#pragma unroll
    for (int ci = 0; ci < 16; ++ci)
        acc += (pool[g * 16 + ci] / c + b2[ci]) * Wfc[ci * 4 + k];
    out[g * 4 + k] = acc;
}

extern "C" void kernel_launch(void* const* d_in, const int* in_sizes, int n_in,
                              void* d_out, int out_size, void* d_ws, size_t ws_size,
                              hipStream_t stream) {
    const float* x   = (const float*)d_in[0];
    const float* W1  = (const float*)d_in[1];
    const float* as1 = (const float*)d_in[2];
    const float* ad1 = (const float*)d_in[3];
    const float* b1  = (const float*)d_in[4];
    const float* W2  = (const float*)d_in[5];
    const float* as2 = (const float*)d_in[6];
    const float* ad2 = (const float*)d_in[7];
    const float* b2  = (const float*)d_in[8];
    const float* Wfc = (const float*)d_in[9];
    const float* bfc = (const float*)d_in[10];
    const int* ei    = (const int*)d_in[11];
    const int* batch = (const int*)d_in[12];
    const int* srcv  = ei;             // edge_index[0]
    const int* dstv  = ei + N_EDGES;   // edge_index[1]

    char* ws = (char*)d_ws;
    size_t o = 0;
    auto alloc = [&](size_t bytes) {
        void* p = ws + o;
        o += (bytes + 255) & ~(size_t)255;
        return p;
    };
    // zero-region first (one memset): cnt, pool, gbin_cursor
    int*    cnt     = (int*)alloc(64 * 4);
    float*  pool    = (float*)alloc(64 * 16 * 4);
    int*    gbin    = (int*)alloc(NBIN * 4);
    size_t  zbytes  = o;
    int*    off     = (int*)alloc((size_t)(N_NODES + 1) * 4);
    int*    csr     = (int*)alloc((size_t)N_EDGES * 4);
    float*  s1      = (float*)alloc((size_t)NPAD * 8 * 4);       // padded for gemm grid
    float2* ap      = (float2*)alloc((size_t)N_NODES * 4 * 8);
    float2* dp      = (float2*)alloc((size_t)N_NODES * 4 * 8);
    float*  prep    = (float*)alloc(1040 * 4);
    // union: binned (CSR build) aliases h2p (gemm onward)
    size_t  ub      = (size_t)NBIN * BINCAP * 8;                 // 19.3 MB
    size_t  hb      = (size_t)N_NODES * 64 * 4;                  // 25.6 MB
    char*   ubase   = (char*)alloc(ub > hb ? ub : hb);
    int2*   binned  = (int2*)ubase;
    __half2* h2p    = (__half2*)ubase;

    hipMemsetAsync(d_ws, 0, zbytes, stream);

    int nbA = (N_EDGES + EPB - 1) / EPB;   // 782

    k_binA<<<nbA, 512, 0, stream>>>(srcv, dstv, batch, gbin, cnt, binned);
    k_binB<<<NBIN, 1024, 0, stream>>>(binned, gbin, off, csr,
                                      W1, as1, ad1, W2, as2, ad2, prep);
    k_layer1<<<N_NODES / 16, 256, 0, stream>>>(x, W1, b1, prep, off, csr, s1, ap, dp);
    k_gemm<<<NPAD / 64, 256, 0, stream>>>(s1, W1, b1, W2, h2p);
    k_layer2<<<N_NODES / 4, 256, 0, stream>>>(h2p, ap, dp, off, csr, batch, pool);
    k_final<<<1, 256, 0, stream>>>(pool, cnt, b2, Wfc, bfc, (float*)d_out);
}

// Round 15
// 274.813 us; speedup vs baseline: 1.6013x; 1.1806x over previous
//
#include <hip/hip_runtime.h>
#include <hip/hip_fp16.h>

#define N_NODES  100000
#define N_EDGES  1600000
#define N_GRAPHS 64

#define BINSH  8
#define NBIN   392          // bins of 256 nodes (last ones empty-guarded)
#define BINCAP 5120         // Poisson(4081) max ~4.4K; safe headroom
#define EPB    2048         // edges per block in k_binA

typedef _Float16 half8 __attribute__((ext_vector_type(8)));
typedef float float4v __attribute__((ext_vector_type(4)));

__device__ __forceinline__ float lrelu(float v) { return v > 0.f ? v : 0.2f * v; }
__device__ __forceinline__ float elu_f(float v) { return v > 0.f ? v : __expf(v) - 1.f; }

// ---- Pass A: coarse-bin edges (dst>>8) into per-bin regions, coalesced runs.
// binned entries packed: (dst_local << 17) | src  (src < 2^17).
__global__ __launch_bounds__(512) void k_binA(
    const int* __restrict__ src, const int* __restrict__ dst,
    const int* __restrict__ batch, int* __restrict__ gbin_cursor,
    int* __restrict__ cnt, int* __restrict__ binned) {
    __shared__ int hist[NBIN], lexcl[NBIN], runbase[NBIN], lcur[NBIN];
    __shared__ int wpart[8];
    __shared__ int gh[N_GRAPHS];
    __shared__ int2 stage[EPB];   // {packed, bin}
    int t = threadIdx.x;
    int e0 = blockIdx.x * EPB;
    for (int b = t; b < NBIN; b += 512) hist[b] = 0;
    if (t < N_GRAPHS) gh[t] = 0;
    __syncthreads();
    int nid = blockIdx.x * 512 + t;   // 782*512 >= N_NODES
    if (nid < N_NODES) atomicAdd(&gh[batch[nid]], 1);
    int e = 4 * t;
    int4 dv = make_int4(0, 0, 0, 0), sv = make_int4(0, 0, 0, 0);
    bool full = (e0 + e + 3 < N_EDGES);
    if (full) {
        dv = *(const int4*)(dst + e0 + e);
        sv = *(const int4*)(src + e0 + e);
        atomicAdd(&hist[dv.x >> BINSH], 1);
        atomicAdd(&hist[dv.y >> BINSH], 1);
        atomicAdd(&hist[dv.z >> BINSH], 1);
        atomicAdd(&hist[dv.w >> BINSH], 1);
    } else {
        for (int k = 0; k < 4; ++k)
            if (e0 + e + k < N_EDGES) atomicAdd(&hist[dst[e0 + e + k] >> BINSH], 1);
    }
    __syncthreads();
    int v = (t < NBIN) ? hist[t] : 0;
    int x = v;
#pragma unroll
    for (int d = 1; d < 64; d <<= 1) {
        int y = __shfl_up(x, d, 64);
        if ((t & 63) >= d) x += y;
    }
    if ((t & 63) == 63) wpart[t >> 6] = x;
    __syncthreads();
    if (t == 0) {
        int a = 0;
        for (int w = 0; w < 8; ++w) { int q = wpart[w]; wpart[w] = a; a += q; }
    }
    __syncthreads();
    int excl = x - v + wpart[t >> 6];
    if (t < NBIN) { lexcl[t] = excl; lcur[t] = excl; }
    __syncthreads();
    if (t < NBIN && v > 0) runbase[t] = atomicAdd(&gbin_cursor[t], v);
    if (t < N_GRAPHS && gh[t]) atomicAdd(&cnt[t], gh[t]);
    __syncthreads();
    if (full) {
        int p, b_;
        b_ = dv.x >> BINSH; p = atomicAdd(&lcur[b_], 1);
        stage[p] = make_int2(((dv.x & 255) << 17) | sv.x, b_);
        b_ = dv.y >> BINSH; p = atomicAdd(&lcur[b_], 1);
        stage[p] = make_int2(((dv.y & 255) << 17) | sv.y, b_);
        b_ = dv.z >> BINSH; p = atomicAdd(&lcur[b_], 1);
        stage[p] = make_int2(((dv.z & 255) << 17) | sv.z, b_);
        b_ = dv.w >> BINSH; p = atomicAdd(&lcur[b_], 1);
        stage[p] = make_int2(((dv.w & 255) << 17) | sv.w, b_);
    } else {
        for (int k = 0; k < 4; ++k) {
            if (e0 + e + k < N_EDGES) {
                int d = dst[e0 + e + k];
                int b_ = d >> BINSH;
                int p = atomicAdd(&lcur[b_], 1);
                stage[p] = make_int2(((d & 255) << 17) | src[e0 + e + k], b_);
            }
        }
    }
    __syncthreads();
    int m = N_EDGES - e0;
    if (m > EPB) m = EPB;
    for (int i = 4 * t; i < 4 * t + 4 && i < m; ++i) {
        int2 pr = stage[i];
        int b_ = pr.y;
        binned[(size_t)b_ * BINCAP + runbase[b_] + (i - lexcl[b_])] = pr.x;
    }
}

// ---- MEGA pass B: counting sort -> off/csr, then IN-BLOCK: layer-1
// (shuffle-reduce, no atomics), exact-fp32 logits, and the verified MFMA
// h2 GEMM for the block's 256 nodes. One kernel replaces three + cuts
// two launch bubbles and all intermediate round-trips except h2p/ap/dp.
__global__ __launch_bounds__(1024) void k_megaB(
    const int* __restrict__ binned, const int* __restrict__ gbin_cursor,
    int* __restrict__ off, int* __restrict__ csr,
    const float* __restrict__ x, const float* __restrict__ W1,
    const float* __restrict__ as1, const float* __restrict__ ad1,
    const float* __restrict__ b1, const float* __restrict__ W2,
    const float* __restrict__ as2, const float* __restrict__ ad2,
    __half2* __restrict__ h2p, float2* __restrict__ ap, float2* __restrict__ dp) {
    __shared__ int hist[256], lstart[256];
    __shared__ int wpart[4];
    __shared__ int s_ebase;
    __shared__ float s1l[256 * 8];          // 8 KB
    __shared__ float smWs[512], smWd[512];  // 4 KB
    __shared__ float smW1[64], smB1[64];
    __shared__ float ws8s[8], wd8s[8];
    __shared__ _Float16 smWT[128 * 72];     // 18 KB  W2^T fp16, +8 pad
    __shared__ _Float16 smA[256 * 72];      // 36 KB  h1a fp16, +8 pad
    int b = blockIdx.x, t = threadIdx.x;
    int count = gbin_cursor[b];
    int node0 = b << BINSH;
    const int* my = binned + (size_t)b * BINCAP;

    // ---- P0: stage constants + zero
    if (t == 0) s_ebase = 0;
    if (t < 256) hist[t] = 0;
    for (int idx = t; idx < 8192; idx += 1024) {     // W2^T fp16
        int c = idx >> 6, k = idx & 63;
        smWT[c * 72 + k] = (_Float16)W2[k * 128 + c];
    }
    {   // Ws / Wd logit matrices (exact fp32)
        int tt = t & 511;
        int k = tt >> 3, h = tt & 7;
        const float* att = (t < 512) ? as2 : ad2;
        float acc = 0.f;
        for (int c = 0; c < 16; ++c)
            acc += W2[k * 128 + h * 16 + c] * att[h * 16 + c];
        if (t < 512) smWs[k * 8 + h] = acc; else smWd[k * 8 + h] = acc;
    }
    if (t < 64) { smW1[t] = W1[t]; smB1[t] = b1[t]; }
    if (t >= 64 && t < 72) {
        int h = t - 64;
        float s = 0.f, d = 0.f;
        for (int c = 0; c < 8; ++c) {
            float w = W1[h * 8 + c];
            s += w * as1[h * 8 + c];
            d += w * ad1[h * 8 + c];
        }
        ws8s[h] = s;
        wd8s[h] = d;
    }
    __syncthreads();

    // ---- P1: ebase + histogram
    if (t < b) atomicAdd(&s_ebase, gbin_cursor[t]);
    for (int i = t; i < count; i += 1024) atomicAdd(&hist[binned[(size_t)b * BINCAP + i] >> 17], 1);
    __syncthreads();

    // ---- P2: 2-barrier scan over 256 keys
    int v = (t < 256) ? hist[t] : 0;
    int xx = v;
#pragma unroll
    for (int d = 1; d < 64; d <<= 1) {
        int y = __shfl_up(xx, d, 64);
        if ((t & 63) >= d) xx += y;
    }
    if (t < 256 && (t & 63) == 63) wpart[t >> 6] = xx;
    __syncthreads();
    if (t == 0) {
        int a = 0;
        for (int w = 0; w < 4; ++w) { int q = wpart[w]; wpart[w] = a; a += q; }
    }
    __syncthreads();
    int ebase = s_ebase;
    int excl = xx - v + ((t < 256) ? wpart[t >> 6] : 0);
    if (t < 256) {
        int n = node0 + t;
        if (n < N_NODES) off[n] = ebase + excl;
        lstart[t] = excl;
        hist[t] = excl;    // cursor
    }
    if (b == 0 && t == 0) off[N_NODES] = N_EDGES;
    __syncthreads();

    // ---- P3: csr fill
    for (int i = t; i < count; i += 1024) {
        int pr = my[i];
        int p = atomicAdd(&hist[pr >> 17], 1);
        csr[ebase + p] = pr & 0x1FFFF;
    }
    __syncthreads();   // csr visible to block; hist[nl] = end cursor

    // ---- P4: layer 1, 4 lanes/node shuffle-reduce (no atomics)
    {
        int nl = t >> 2, c = t & 3;
        int n = node0 + nl;
        float ws[8], wd[8];
#pragma unroll
        for (int h = 0; h < 8; ++h) { ws[h] = ws8s[h]; wd[h] = wd8s[h]; }
        float xn = (n < N_NODES) ? x[n] : 0.f;
        float num[8], den[8];
#pragma unroll
        for (int h = 0; h < 8; ++h) { num[h] = 0.f; den[h] = 0.f; }
        if (c == 0 && n < N_NODES) {  // self loop
#pragma unroll
            for (int h = 0; h < 8; ++h) {
                float w = __expf(lrelu(xn * ws[h] + xn * wd[h]));
                den[h] = w;
                num[h] = w * xn;
            }
        }
        int st = lstart[nl], en = hist[nl];
        for (int j = st + c; j < en; j += 4) {
            int s = csr[ebase + j];
            float xs = x[s];
#pragma unroll
            for (int h = 0; h < 8; ++h) {
                float w = __expf(lrelu(xs * ws[h] + xn * wd[h]));
                den[h] += w;
                num[h] += w * xs;
            }
        }
#pragma unroll
        for (int d = 1; d < 4; d <<= 1) {
#pragma unroll
            for (int h = 0; h < 8; ++h) {
                num[h] += __shfl_xor(num[h], d, 64);
                den[h] += __shfl_xor(den[h], d, 64);
            }
        }
        if (c == 0) {
#pragma unroll
            for (int h = 0; h < 8; ++h)
                s1l[nl * 8 + h] = (n < N_NODES) ? num[h] / den[h] : 0.f;
        }
    }
    __syncthreads();

    // ---- P5: exact-fp32 logits (lane j of 4 -> heads j, j+4) + P6: smA fill
    {
        int nl = t >> 2, j = t & 3;
        int n = node0 + nl;
        if (n < N_NODES) {
            float pSA = 0.f, pSB = 0.f, pDA = 0.f, pDB = 0.f;
#pragma unroll 8
            for (int k = 0; k < 64; ++k) {
                float h1a = elu_f(s1l[nl * 8 + (k >> 3)] * smW1[k] + smB1[k]);
                pSA += h1a * smWs[k * 8 + j];
                pSB += h1a * smWs[k * 8 + j + 4];
                pDA += h1a * smWd[k * 8 + j];
                pDB += h1a * smWd[k * 8 + j + 4];
            }
            ap[n * 4 + j] = make_float2(pSA, pSB);
            dp[n * 4 + j] = make_float2(pDA, pDB);
        }
    }
    for (int i = t; i < 256 * 64; i += 1024) {   // h1a fp16 for MFMA A
        int m = i >> 6, k = i & 63;
        smA[m * 72 + k] = (_Float16)elu_f(s1l[m * 8 + (k >> 3)] * smW1[k] + smB1[k]);
    }
    __syncthreads();

    // ---- P7: MFMA h2 GEMM, 16 waves x 16 nodes (R13/R14-verified layouts)
    {
        int wave = t >> 6, lane = t & 63;
        int quad = lane >> 4, m15 = lane & 15;
        half8 a0 = *reinterpret_cast<const half8*>(&smA[(wave * 16 + m15) * 72 + quad * 8]);
        half8 a1 = *reinterpret_cast<const half8*>(&smA[(wave * 16 + m15) * 72 + 32 + quad * 8]);
        float4v acc[8];
#pragma unroll
        for (int tl = 0; tl < 8; ++tl) {
            half8 b0 = *reinterpret_cast<const half8*>(&smWT[(tl * 16 + m15) * 72 + quad * 8]);
            half8 b1v = *reinterpret_cast<const half8*>(&smWT[(tl * 16 + m15) * 72 + 32 + quad * 8]);
            float4v c = {0.f, 0.f, 0.f, 0.f};
            c = __builtin_amdgcn_mfma_f32_16x16x32_f16(a0, b0, c, 0, 0, 0);
            c = __builtin_amdgcn_mfma_f32_16x16x32_f16(a1, b1v, c, 0, 0, 0);
            acc[tl] = c;
        }
#pragma unroll
        for (int tl = 0; tl < 4; ++tl) {
#pragma unroll
            for (int reg = 0; reg < 4; ++reg) {
                int n = node0 + wave * 16 + quad * 4 + reg;
                if (n < N_NODES)
                    h2p[n * 64 + tl * 16 + m15] =
                        __floats2half2_rn(acc[tl][reg], acc[tl + 4][reg]);
            }
        }
    }
}

// ---- Layer 2 aggregation: frozen at the R10 structure (~110us, pinned by
// the random-gather path at ~2.4 TB/s).
__global__ __launch_bounds__(256, 8) void k_layer2(
    const __half2* __restrict__ h2p, const float2* __restrict__ ap,
    const float2* __restrict__ dp, const int* __restrict__ off,
    const int* __restrict__ csr, const int* __restrict__ batch,
    float* __restrict__ pool) {
    __shared__ float smv[4][16];
    __shared__ int smg[4];
    const float* apf = (const float*)ap;   // flat: node*8 + 2*(h&3) + (h>>2)
    const float* dpf = (const float*)dp;
    int t = threadIdx.x;
    int wid = t >> 6, l = t & 63;
    int n = blockIdx.x * 4 + wid;  // grid exact: 25000*4 == N_NODES
    int hA = l >> 4;
    int hh = l & 7;
    int j8 = l >> 3;
    int fidx = 2 * (hh & 3) + (hh >> 2);
    float dn = dpf[n * 8 + fidx];

    float2 ad = dp[n * 4 + hA];
    float2 an = ap[n * 4 + hA];
    float wA = __expf(lrelu(an.x + ad.x));
    float wB = __expf(lrelu(an.y + ad.y));
    float2 hn = __half22float2(h2p[n * 64 + l]);
    float accA = wA * hn.x, accB = wB * hn.y;
    float denTA = wA, denTB = wB;
    float wsum = 0.f;

    int b = off[n];
    int deg = off[n + 1] - b;
    for (int base = 0; base < deg; base += 64) {
        int rem = deg - base;
        if (rem > 64) rem = 64;
        int sl = (l < rem) ? csr[b + base + l] : 0;
        int g = 0;
        for (; g + 8 <= rem; g += 8) {
            int sg = __shfl(sl, g + j8, 64);
            float w = __expf(lrelu(apf[sg * 8 + fidx] + dn));
            wsum += w;
#pragma unroll
            for (int j2 = 0; j2 < 8; ++j2) {
                int s = __builtin_amdgcn_readlane(sl, g + j2);
                float wa = __shfl(w, j2 * 8 + hA, 64);
                float wb = __shfl(w, j2 * 8 + hA + 4, 64);
                float2 gg = __half22float2(h2p[s * 64 + l]);
                accA = fmaf(wa, gg.x, accA);
                accB = fmaf(wb, gg.y, accB);
            }
        }
        if (g < rem) {
            int cnt = rem - g;
            int jj = (j8 < cnt) ? j8 : 0;
            int sg = __shfl(sl, g + jj, 64);
            float w = (j8 < cnt) ? __expf(lrelu(apf[sg * 8 + fidx] + dn)) : 0.f;
            wsum += w;
            for (int j2 = 0; j2 < cnt; ++j2) {
                int s = __builtin_amdgcn_readlane(sl, g + j2);
                float wa = __shfl(w, j2 * 8 + hA, 64);
                float wb = __shfl(w, j2 * 8 + hA + 4, 64);
                float2 gg = __half22float2(h2p[s * 64 + l]);
                accA = fmaf(wa, gg.x, accA);
                accB = fmaf(wb, gg.y, accB);
            }
        }
    }
    wsum += __shfl_xor(wsum, 8, 64);
    wsum += __shfl_xor(wsum, 16, 64);
    wsum += __shfl_xor(wsum, 32, 64);
    float denA = denTA + __shfl(wsum, hA, 64);
    float denB = denTB + __shfl(wsum, hA + 4, 64);

    float v = accA / denA + accB / denB;
    v += __shfl_xor(v, 16, 64);
    v += __shfl_xor(v, 32, 64);
    v *= 0.125f;
    if (l < 16) smv[wid][l] = v;
    if (l == 0) smg[wid] = batch[n];
    __syncthreads();
    if (t < 64) {
        int w = t >> 4, c = t & 15;
        int g = smg[w];
        bool leader = true;
        for (int w2 = 0; w2 < w; ++w2)
            if (smg[w2] == g) { leader = false; break; }
        if (leader) {
            float s = smv[w][c];
            for (int w2 = w + 1; w2 < 4; ++w2)
                if (smg[w2] == g) s += smv[w2][c];
            atomicAdd(&pool[g * 16 + c], s);
        }
    }
}

// ---- final: pooled mean (+b2) @ Wfc + bfc -> [64,4]
__global__ void k_final(const float* __restrict__ pool, const int* __restrict__ cnt,
                        const float* __restrict__ b2, const float* __restrict__ Wfc,
                        const float* __restrict__ bfc, float* __restrict__ out) {
    int t = threadIdx.x;
    int g = t >> 2, k = t & 3;
    float c = (float)(cnt[g] > 0 ? cnt[g] : 1);
    float acc = bfc[k];
#pragma unroll
    for (int ci = 0; ci < 16; ++ci)
        acc += (pool[g * 16 + ci] / c + b2[ci]) * Wfc[ci * 4 + k];
    out[g * 4 + k] = acc;
}

extern "C" void kernel_launch(void* const* d_in, const int* in_sizes, int n_in,
                              void* d_out, int out_size, void* d_ws, size_t ws_size,
                              hipStream_t stream) {
    const float* x   = (const float*)d_in[0];
    const float* W1  = (const float*)d_in[1];
    const float* as1 = (const float*)d_in[2];
    const float* ad1 = (const float*)d_in[3];
    const float* b1  = (const float*)d_in[4];
    const float* W2  = (const float*)d_in[5];
    const float* as2 = (const float*)d_in[6];
    const float* ad2 = (const float*)d_in[7];
    const float* b2  = (const float*)d_in[8];
    const float* Wfc = (const float*)d_in[9];
    const float* bfc = (const float*)d_in[10];
    const int* ei    = (const int*)d_in[11];
    const int* batch = (const int*)d_in[12];
    const int* srcv  = ei;             // edge_index[0]
    const int* dstv  = ei + N_EDGES;   // edge_index[1]

    char* ws = (char*)d_ws;
    size_t o = 0;
    auto alloc = [&](size_t bytes) {
        void* p = ws + o;
        o += (bytes + 255) & ~(size_t)255;
        return p;
    };
    // zero-region first (one memset): cnt, pool, gbin_cursor
    int*    cnt     = (int*)alloc(64 * 4);
    float*  pool    = (float*)alloc(64 * 16 * 4);
    int*    gbin    = (int*)alloc(NBIN * 4);
    size_t  zbytes  = o;
    int*    off     = (int*)alloc((size_t)(N_NODES + 1) * 4);
    int*    csr     = (int*)alloc((size_t)N_EDGES * 4);
    float2* ap      = (float2*)alloc((size_t)N_NODES * 4 * 8);
    float2* dp      = (float2*)alloc((size_t)N_NODES * 4 * 8);
    int*    binned  = (int*)alloc((size_t)NBIN * BINCAP * 4);    // 8.0 MB packed
    __half2* h2p    = (__half2*)alloc((size_t)N_NODES * 64 * 4); // 25.6 MB

    hipMemsetAsync(d_ws, 0, zbytes, stream);

    int nbA = (N_EDGES + EPB - 1) / EPB;   // 782

    k_binA<<<nbA, 512, 0, stream>>>(srcv, dstv, batch, gbin, cnt, binned);
    k_megaB<<<NBIN, 1024, 0, stream>>>(binned, gbin, off, csr,
                                       x, W1, as1, ad1, b1, W2, as2, ad2,
                                       h2p, ap, dp);
    k_layer2<<<N_NODES / 4, 256, 0, stream>>>(h2p, ap, dp, off, csr, batch, pool);
    k_final<<<1, 256, 0, stream>>>(pool, cnt, b2, Wfc, bfc, (float*)d_out);
}